// Round 2
// 1067.145 us; speedup vs baseline: 1.0098x; 1.0098x over previous
//
#include <hip/hip_runtime.h>

// Problem constants (from reference): M=12, N=8, C=1024, D=64, B=32, S=512
#define M_R   12
#define N_E   8
#define C_DIM 1024
#define D_DIM 64
#define B_SZ  32
#define S_SZ  512
#define TS    128   // s-rows per block
#define PAD   72    // LDS row pitch (bf16 elems): multiple of 8 for 16B-aligned b128

typedef __bf16 bf16x8 __attribute__((ext_vector_type(8)));
typedef float  floatx4 __attribute__((ext_vector_type(4)));

__device__ __forceinline__ unsigned short f2bf(float f) {
    // round-to-nearest-even fp32 -> bf16
    unsigned int u = __float_as_uint(f);
    u += 0x7FFFu + ((u >> 16) & 1u);
    return (unsigned short)(u >> 16);
}

// ---------------------------------------------------------------------------
// Pre-pass 1: x [B,S,C] fp32 -> bf16 (elementwise, 8 elems/thread)
// ---------------------------------------------------------------------------
__global__ __launch_bounds__(256) void cvt_x(const float* __restrict__ x,
                                             unsigned short* __restrict__ xb) {
    const int i = blockIdx.x * 256 + threadIdx.x;       // index of 8-elem group
    const float4* p = (const float4*)x + (size_t)i * 2;
    float4 a = p[0], b = p[1];
    unsigned short h[8] __attribute__((aligned(16)));
    h[0] = f2bf(a.x); h[1] = f2bf(a.y); h[2] = f2bf(a.z); h[3] = f2bf(a.w);
    h[4] = f2bf(b.x); h[5] = f2bf(b.y); h[6] = f2bf(b.z); h[7] = f2bf(b.w);
    ((uint4*)xb)[i] = *(const uint4*)h;
}

// ---------------------------------------------------------------------------
// Pre-pass 2: down_w [M,N,C,D] fp32 -> wdT [M,N,D,C] bf16 (transpose per slice)
// one 64(c)x64(d) tile per block; grid = M*N*16
// ---------------------------------------------------------------------------
__global__ __launch_bounds__(256) void cvt_wd(const float* __restrict__ wd,
                                              unsigned short* __restrict__ wdT) {
    __shared__ unsigned short T[64 * 65];
    const int blk   = blockIdx.x;
    const int slice = blk >> 4;
    const int c0    = (blk & 15) * 64;
    const float*    src = wd  + (size_t)slice * (C_DIM * D_DIM);
    unsigned short* dst = wdT + (size_t)slice * (C_DIM * D_DIM);
    const int t = threadIdx.x;

    #pragma unroll
    for (int i = 0; i < 4; ++i) {
        int f4 = i * 256 + t;           // 0..1023
        int c  = f4 >> 4;               // 0..63
        int d4 = (f4 & 15) << 2;        // 0..60
        float4 v = *(const float4*)(src + (size_t)(c0 + c) * D_DIM + d4);
        T[(d4 + 0) * 65 + c] = f2bf(v.x);
        T[(d4 + 1) * 65 + c] = f2bf(v.y);
        T[(d4 + 2) * 65 + c] = f2bf(v.z);
        T[(d4 + 3) * 65 + c] = f2bf(v.w);
    }
    __syncthreads();
    const int d   = t >> 2;             // 0..63
    const int c16 = (t & 3) << 4;       // 0,16,32,48
    unsigned short tmp[16] __attribute__((aligned(16)));
    #pragma unroll
    for (int j = 0; j < 16; ++j) tmp[j] = T[d * 65 + c16 + j];
    *(uint4*)(dst + (size_t)d * C_DIM + c0 + c16)     = ((const uint4*)tmp)[0];
    *(uint4*)(dst + (size_t)d * C_DIM + c0 + c16 + 8) = ((const uint4*)tmp)[1];
}

// ---------------------------------------------------------------------------
// Pre-pass 3: up_w [M,N,D,C] fp32 -> wuT [M,N,C,D] bf16 (transpose per slice)
// one 64(d)x64(c) tile per block; grid = M*N*16
// ---------------------------------------------------------------------------
__global__ __launch_bounds__(256) void cvt_wu(const float* __restrict__ wu,
                                              unsigned short* __restrict__ wuT) {
    __shared__ unsigned short T[64 * 65];
    const int blk   = blockIdx.x;
    const int slice = blk >> 4;
    const int c0    = (blk & 15) * 64;
    const float*    src = wu  + (size_t)slice * (D_DIM * C_DIM);
    unsigned short* dst = wuT + (size_t)slice * (D_DIM * C_DIM);
    const int t = threadIdx.x;

    #pragma unroll
    for (int i = 0; i < 4; ++i) {
        int f4 = i * 256 + t;           // 0..1023
        int d  = f4 >> 4;               // 0..63
        int c4 = (f4 & 15) << 2;        // 0..60
        float4 v = *(const float4*)(src + (size_t)d * C_DIM + c0 + c4);
        T[(c4 + 0) * 65 + d] = f2bf(v.x);
        T[(c4 + 1) * 65 + d] = f2bf(v.y);
        T[(c4 + 2) * 65 + d] = f2bf(v.z);
        T[(c4 + 3) * 65 + d] = f2bf(v.w);
    }
    __syncthreads();
    const int c   = t >> 2;             // 0..63
    const int d16 = (t & 3) << 4;       // 0,16,32,48
    unsigned short tmp[16] __attribute__((aligned(16)));
    #pragma unroll
    for (int j = 0; j < 16; ++j) tmp[j] = T[c * 65 + d16 + j];
    *(uint4*)(dst + (size_t)(c0 + c) * D_DIM + d16)     = ((const uint4*)tmp)[0];
    *(uint4*)(dst + (size_t)(c0 + c) * D_DIM + d16 + 8) = ((const uint4*)tmp)[1];
}

// ---------------------------------------------------------------------------
// Main fused kernel (v2): all operands pre-converted bf16, MFMA fragments
// loaded DIRECTLY from global (L1/L2-hot). Only LDS use: Z' exchange
// (C-layout -> A-fragment layout); one barrier total.
// ---------------------------------------------------------------------------
__global__ __launch_bounds__(256) void adapter_fused_v2(
    const unsigned short* __restrict__ xb_all,  // [B,S,C]   bf16
    const int*            __restrict__ eidx,    // [M,B]
    const unsigned short* __restrict__ wdT,     // [M,N,D,C] bf16 (Wd^T)
    const float*          __restrict__ down_b,  // [M,N,D]
    const unsigned short* __restrict__ wuT,     // [M,N,C,D] bf16 (Wu^T)
    float*                __restrict__ out)     // [M,B,S,C]
{
    __shared__ unsigned short Zs[TS * PAD];     // Z' tile, bf16

    const int t    = threadIdx.x;
    const int wave = t >> 6;
    const int lane = t & 63;
    const int l15  = lane & 15;
    const int quad = lane >> 4;
    const int srow = wave * 32;

    const int bid = blockIdx.x;
    const int m  = bid % M_R;      // m innermost: 12 adjacent blocks share an x tile
    const int p  = bid / M_R;
    const int b  = p >> 2;
    const int sc = p & 3;
    const int s0 = sc * TS;

    const int e = eidx[m * B_SZ + b];

    const unsigned short* xb   = xb_all + ((size_t)(b * S_SZ + s0)) * C_DIM;
    const unsigned short* wd   = wdT    + (size_t)(m * N_E + e) * (C_DIM * D_DIM);
    const float*          bias = down_b + (size_t)(m * N_E + e) * D_DIM;
    const unsigned short* wu   = wuT    + (size_t)(m * N_E + e) * (C_DIM * D_DIM);
    float*                outp = out    + ((size_t)((m * B_SZ + b) * S_SZ + s0)) * C_DIM;

    floatx4 acc[2][4];
    #pragma unroll
    for (int i = 0; i < 2; ++i)
        #pragma unroll
        for (int j = 0; j < 4; ++j)
            acc[i][j] = (floatx4){0.f, 0.f, 0.f, 0.f};

    // ---------------- GEMM1: Z[128,64] = X[128,1024] * Wd[1024,64] ----------
    // A fragments: row = srow + (mt*16) + l15, k = kk + ks + quad*8  (16B/lane)
    // B fragments: row d = nt*16 + l15 of Wd^T, same k                (16B/lane)
    #pragma unroll 2
    for (int kk = 0; kk < C_DIM; kk += 64) {
        #pragma unroll
        for (int ks = 0; ks < 64; ks += 32) {
            const int k = kk + ks + quad * 8;
            bf16x8 a0 = *(const bf16x8*)(xb + (size_t)(srow +      l15) * C_DIM + k);
            bf16x8 a1 = *(const bf16x8*)(xb + (size_t)(srow + 16 + l15) * C_DIM + k);
            #pragma unroll
            for (int nt = 0; nt < 4; ++nt) {
                bf16x8 bf = *(const bf16x8*)(wd + (size_t)(nt * 16 + l15) * C_DIM + k);
                acc[0][nt] = __builtin_amdgcn_mfma_f32_16x16x32_bf16(a0, bf, acc[0][nt], 0, 0, 0);
                acc[1][nt] = __builtin_amdgcn_mfma_f32_16x16x32_bf16(a1, bf, acc[1][nt], 0, 0, 0);
            }
        }
    }

    // ---------------- bias + swish, Z' -> LDS ----------
    float bv[4];
    #pragma unroll
    for (int nt = 0; nt < 4; ++nt) bv[nt] = bias[nt * 16 + l15];

    #pragma unroll
    for (int mt = 0; mt < 2; ++mt)
        #pragma unroll
        for (int nt = 0; nt < 4; ++nt)
            #pragma unroll
            for (int r = 0; r < 4; ++r) {
                float z  = acc[mt][nt][r] + bv[nt];
                float sw = z / (1.0f + __expf(-z));
                int s = srow + mt * 16 + quad * 4 + r;   // C/D map: row=quad*4+reg
                int d = nt * 16 + l15;                   //          col=lane&15
                Zs[s * PAD + d] = f2bf(sw);
            }
    // single barrier: guarantees ds_write->ds_read ordering (cheap; once per block)
    __syncthreads();

    bf16x8 za[2][2];
    #pragma unroll
    for (int mt = 0; mt < 2; ++mt)
        #pragma unroll
        for (int ki = 0; ki < 2; ++ki)
            za[mt][ki] = *(const bf16x8*)&Zs[(srow + mt * 16 + l15) * PAD + ki * 32 + quad * 8];

    // ---------------- GEMM2: U[128,1024] = Z'[128,64] * Wu[64,1024] ----------
    // B fragments: row c = c0 + nt*16 + l15 of Wu^T, k = ki*32 + quad*8
    for (int ci = 0; ci < 16; ++ci) {
        const int c0 = ci * 64;

        floatx4 acc2[2][4];
        #pragma unroll
        for (int i = 0; i < 2; ++i)
            #pragma unroll
            for (int j = 0; j < 4; ++j)
                acc2[i][j] = (floatx4){0.f, 0.f, 0.f, 0.f};

        #pragma unroll
        for (int ki = 0; ki < 2; ++ki) {
            #pragma unroll
            for (int nt = 0; nt < 4; ++nt) {
                bf16x8 bf = *(const bf16x8*)(wu + (size_t)(c0 + nt * 16 + l15) * D_DIM
                                                + ki * 32 + quad * 8);
                acc2[0][nt] = __builtin_amdgcn_mfma_f32_16x16x32_bf16(za[0][ki], bf, acc2[0][nt], 0, 0, 0);
                acc2[1][nt] = __builtin_amdgcn_mfma_f32_16x16x32_bf16(za[1][ki], bf, acc2[1][nt], 0, 0, 0);
            }
        }

        #pragma unroll
        for (int mt = 0; mt < 2; ++mt)
            #pragma unroll
            for (int nt = 0; nt < 4; ++nt)
                #pragma unroll
                for (int r = 0; r < 4; ++r) {
                    int s = srow + mt * 16 + quad * 4 + r;
                    int c = c0 + nt * 16 + l15;
                    outp[(size_t)s * C_DIM + c] = acc2[mt][nt][r];
                }
    }
}

// ---------------------------------------------------------------------------
// Legacy fallback (previous best kernel) — used if workspace is too small.
// ---------------------------------------------------------------------------
__global__ __launch_bounds__(256) void adapter_fused(
    const float* __restrict__ x,        // [B,S,C]
    const int*   __restrict__ eidx,     // [M,B]
    const float* __restrict__ down_w,   // [M,N,C,D]
    const float* __restrict__ down_b,   // [M,N,D]
    const float* __restrict__ up_w,     // [M,N,D,C]
    float*       __restrict__ out)      // [M,B,S,C]
{
    __shared__ unsigned short Xs[TS * PAD];
    __shared__ unsigned short Wt[D_DIM * PAD];
    __shared__ float bias_s[D_DIM];

    const int t    = threadIdx.x;
    const int wave = t >> 6;
    const int lane = t & 63;
    const int l15  = lane & 15;
    const int quad = lane >> 4;
    const int srow = wave * 32;

    const int bid = blockIdx.x;
    const int m  = bid % M_R;
    const int p  = bid / M_R;
    const int b  = p >> 2;
    const int sc = p & 3;
    const int s0 = sc * TS;

    const int e = eidx[m * B_SZ + b];

    const float* xb   = x      + (b * S_SZ + s0) * C_DIM;
    const float* wd   = down_w + (m * N_E + e) * (C_DIM * D_DIM);
    const float* bias = down_b + (m * N_E + e) * D_DIM;
    const float* wu   = up_w   + (m * N_E + e) * (D_DIM * C_DIM);
    float*       outp = out    + ((m * B_SZ + b) * S_SZ + s0) * C_DIM;

    if (t < D_DIM) bias_s[t] = bias[t];

    floatx4 acc[2][4];
    #pragma unroll
    for (int i = 0; i < 2; ++i)
        #pragma unroll
        for (int j = 0; j < 4; ++j)
            acc[i][j] = (floatx4){0.f, 0.f, 0.f, 0.f};

    for (int kk = 0; kk < C_DIM; kk += 64) {
        #pragma unroll
        for (int i = 0; i < 8; ++i) {
            int f4 = i * 256 + t;
            int s  = f4 >> 4;
            int k4 = (f4 & 15) << 2;
            float4 v = *(const float4*)(xb + s * C_DIM + kk + k4);
            ushort4 h;
            h.x = f2bf(v.x); h.y = f2bf(v.y); h.z = f2bf(v.z); h.w = f2bf(v.w);
            *(ushort4*)&Xs[s * PAD + k4] = h;
        }
        #pragma unroll
        for (int i = 0; i < 4; ++i) {
            int f4 = i * 256 + t;
            int c  = f4 >> 4;
            int d4 = (f4 & 15) << 2;
            float4 v = *(const float4*)(wd + (kk + c) * D_DIM + d4);
            Wt[(d4 + 0) * PAD + c] = f2bf(v.x);
            Wt[(d4 + 1) * PAD + c] = f2bf(v.y);
            Wt[(d4 + 2) * PAD + c] = f2bf(v.z);
            Wt[(d4 + 3) * PAD + c] = f2bf(v.w);
        }
        __syncthreads();

        #pragma unroll
        for (int ks = 0; ks < 64; ks += 32) {
            bf16x8 a0 = *(const bf16x8*)&Xs[(srow +      l15) * PAD + ks + quad * 8];
            bf16x8 a1 = *(const bf16x8*)&Xs[(srow + 16 + l15) * PAD + ks + quad * 8];
            #pragma unroll
            for (int nt = 0; nt < 4; ++nt) {
                bf16x8 bf = *(const bf16x8*)&Wt[(nt * 16 + l15) * PAD + ks + quad * 8];
                acc[0][nt] = __builtin_amdgcn_mfma_f32_16x16x32_bf16(a0, bf, acc[0][nt], 0, 0, 0);
                acc[1][nt] = __builtin_amdgcn_mfma_f32_16x16x32_bf16(a1, bf, acc[1][nt], 0, 0, 0);
            }
        }
        __syncthreads();
    }

    #pragma unroll
    for (int mt = 0; mt < 2; ++mt)
        #pragma unroll
        for (int nt = 0; nt < 4; ++nt)
            #pragma unroll
            for (int r = 0; r < 4; ++r) {
                float z  = acc[mt][nt][r] + bias_s[nt * 16 + l15];
                float sw = z / (1.0f + __expf(-z));
                int s = srow + mt * 16 + quad * 4 + r;
                int d = nt * 16 + l15;
                Xs[s * PAD + d] = f2bf(sw);
            }
    __syncthreads();

    bf16x8 za[2][2];
    #pragma unroll
    for (int mt = 0; mt < 2; ++mt)
        #pragma unroll
        for (int ki = 0; ki < 2; ++ki)
            za[mt][ki] = *(const bf16x8*)&Xs[(srow + mt * 16 + l15) * PAD + ki * 32 + quad * 8];

    for (int ci = 0; ci < 16; ++ci) {
        int c0 = ci * 64;
        #pragma unroll
        for (int i = 0; i < 4; ++i) {
            int f4 = i * 256 + t;
            int d  = f4 >> 4;
            int c4 = (f4 & 15) << 2;
            float4 v = *(const float4*)(wu + d * C_DIM + c0 + c4);
            Wt[(c4 + 0) * PAD + d] = f2bf(v.x);
            Wt[(c4 + 1) * PAD + d] = f2bf(v.y);
            Wt[(c4 + 2) * PAD + d] = f2bf(v.z);
            Wt[(c4 + 3) * PAD + d] = f2bf(v.w);
        }
        __syncthreads();

        floatx4 acc2[2][4];
        #pragma unroll
        for (int i = 0; i < 2; ++i)
            #pragma unroll
            for (int j = 0; j < 4; ++j)
                acc2[i][j] = (floatx4){0.f, 0.f, 0.f, 0.f};

        #pragma unroll
        for (int ki = 0; ki < 2; ++ki) {
            #pragma unroll
            for (int nt = 0; nt < 4; ++nt) {
                bf16x8 bf = *(const bf16x8*)&Wt[(nt * 16 + l15) * PAD + ki * 32 + quad * 8];
                acc2[0][nt] = __builtin_amdgcn_mfma_f32_16x16x32_bf16(za[0][ki], bf, acc2[0][nt], 0, 0, 0);
                acc2[1][nt] = __builtin_amdgcn_mfma_f32_16x16x32_bf16(za[1][ki], bf, acc2[1][nt], 0, 0, 0);
            }
        }

        #pragma unroll
        for (int mt = 0; mt < 2; ++mt)
            #pragma unroll
            for (int nt = 0; nt < 4; ++nt)
                #pragma unroll
                for (int r = 0; r < 4; ++r) {
                    int s = srow + mt * 16 + quad * 4 + r;
                    int c = c0 + nt * 16 + l15;
                    outp[s * C_DIM + c] = acc2[mt][nt][r];
                }
        __syncthreads();
    }
}

extern "C" void kernel_launch(void* const* d_in, const int* in_sizes, int n_in,
                              void* d_out, int out_size, void* d_ws, size_t ws_size,
                              hipStream_t stream) {
    const float* x      = (const float*)d_in[0];
    const int*   eidx   = (const int*)d_in[1];
    const float* down_w = (const float*)d_in[2];
    const float* down_b = (const float*)d_in[3];
    const float* up_w   = (const float*)d_in[4];
    float*       out    = (float*)d_out;

    const int grid = M_R * B_SZ * (S_SZ / TS);   // 12*32*4 = 1536 blocks

    const size_t XBE = (size_t)B_SZ * S_SZ * C_DIM;          // 16,777,216 bf16
    const size_t WE  = (size_t)M_R * N_E * C_DIM * D_DIM;    //  6,291,456 bf16 each
    const size_t REQ = (XBE + 2 * WE) * sizeof(unsigned short); // ~56 MB

    if (d_ws != nullptr && ws_size >= REQ) {
        unsigned short* xb  = (unsigned short*)d_ws;
        unsigned short* wdt = xb  + XBE;
        unsigned short* wut = wdt + WE;

        cvt_x <<<(int)(XBE / 8 / 256), 256, 0, stream>>>(x, xb);          // 8192 blocks
        cvt_wd<<<M_R * N_E * 16,       256, 0, stream>>>(down_w, wdt);    // 1536 blocks
        cvt_wu<<<M_R * N_E * 16,       256, 0, stream>>>(up_w,   wut);    // 1536 blocks
        adapter_fused_v2<<<grid, 256, 0, stream>>>(xb, eidx, wdt, down_b, wut, out);
    } else {
        adapter_fused<<<grid, 256, 0, stream>>>(x, eidx, down_w, down_b, up_w, out);
    }
}